// Round 2
// baseline (311.146 us; speedup 1.0000x reference)
//
#include <hip/hip_runtime.h>
#include <hip/hip_bf16.h>
#include <math.h>

// ---------------- problem constants ----------------
#define NB 4          // batch
#define LQ 1000       // queries
#define NHEAD 8
#define DHEAD 32
#define DMODEL 256
#define PSUM 64       // points per head (4 levels x 16)
#define STOT 19822    // total spatial size
#define IMGF 976.0f
#define GK 256        // K dim of all GEMMs

__device__ __constant__ int c_LH[4] = {122, 61, 31, 16};
__device__ __constant__ int c_LW[4] = {122, 61, 31, 16};
__device__ __constant__ int c_LST[4] = {0, 14884, 18605, 19566};

typedef __attribute__((ext_vector_type(8))) short bf16x8;
typedef __attribute__((ext_vector_type(4))) float f32x4;

__device__ inline unsigned int pk2(float a, float b) {
    unsigned short ua = __bfloat16_as_ushort(__float2bfloat16(a));
    unsigned short ub = __bfloat16_as_ushort(__float2bfloat16(b));
    return (unsigned int)ua | ((unsigned int)ub << 16);
}

// ---------------- setup: per-batch constant matrices ----------------
__global__ void setup_consts(const float* __restrict__ p_pfws,
                             const float* __restrict__ pt,
                             float* __restrict__ consts) {
    int n = threadIdx.x;
    if (n >= NB) return;
    const float* P1 = p_pfws + n * 12;
    const float* P2 = p_pfws + (n ^ 1) * 12;
    const float* T  = pt + n * 6;
    const float* T2 = pt + (n ^ 1) * 6;
    float* C = consts + n * 48;
    float det = T[0]*T[4] - T[1]*T[3];
    float idet = 1.0f/det;
    C[0] =  T[4]*idet; C[1] = -T[1]*idet;
    C[2] = -T[3]*idet; C[3] =  T[0]*idet;
    C[4] = T[2]; C[5] = T[5];
    float a=P1[0], b=P1[1], c=P1[2];
    float d=P1[4], e=P1[5], f=P1[6];
    float g=P1[8], h=P1[9], i=P1[10];
    float b10=P1[3], b11=P1[7], b12=P1[11];
    float A_=e*i-f*h, B_=c*h-b*i, Cc=b*f-c*e;
    float D_=f*g-d*i, E_=a*i-c*g, F_=c*d-a*f;
    float G_=d*h-e*g, H_=b*g-a*h, I_=a*e-b*d;
    float det3 = a*A_ + b*D_ + c*G_;
    float id3 = 1.0f/det3;
    C[6]=A_*id3;  C[7]=B_*id3;  C[8]=Cc*id3;
    C[9]=D_*id3;  C[10]=E_*id3; C[11]=F_*id3;
    C[12]=G_*id3; C[13]=H_*id3; C[14]=I_*id3;
    C[15]=b10; C[16]=b11; C[17]=b12;
    for (int k = 0; k < 12; ++k) C[18+k] = P2[k];
    float cam0 = -(C[6]*b10  + C[7]*b11  + C[8]*b12);
    float cam1 = -(C[9]*b10  + C[10]*b11 + C[11]*b12);
    float cam2 = -(C[12]*b10 + C[13]*b11 + C[14]*b12);
    float y0 = P2[0]*cam0 + P2[1]*cam1 + P2[2]*cam2  + P2[3];
    float y1 = P2[4]*cam0 + P2[5]*cam1 + P2[6]*cam2  + P2[7];
    float y2 = P2[8]*cam0 + P2[9]*cam1 + P2[10]*cam2 + P2[11];
    float inv = 1.0f/(y2 + 1e-8f);
    C[30] = y0*inv; C[31] = y1*inv;
    for (int k = 0; k < 6; ++k) C[32+k] = T2[k];
}

// ---------------- bf16 MFMA GEMM: value[i,o] = bf16( X[i,:]·W[o,:] + bias[o] ) ----------------
// X fp32 MxK row-major (converted on the fly), W fp32 NxK row-major, K=256.
// BM=128, BN=64, BK=64. 256 threads = 4 waves (2x2), each wave 64x32 out (4x2 frags).
// LDS: A [128][64] bf16 (16 KB) + B [64][64] bf16 (8 KB), XOR-swizzled (G4).
#define VB_BM 128
#define VB_BN 64
#define VB_BK 64
#define VB_BOFF 16384

__global__ __launch_bounds__(256)
void gemm_val_bf16(const float* __restrict__ X, const float* __restrict__ W,
                   const float* __restrict__ bias, unsigned short* __restrict__ out,
                   int M) {
    __shared__ char smem[16384 + 8192];
    int i0 = blockIdx.x * VB_BM;
    int o0 = blockIdx.y * VB_BN;
    int tid = threadIdx.x;
    int lane = tid & 63;
    int w = tid >> 6;
    int wr = w >> 1, wc = w & 1;

    f32x4 acc[4][2] = {};

    // staging coords
    int ar = tid >> 1;          // A row 0..127
    int ah = tid & 1;           // A k-half (32 floats each)
    int br = tid & 63;          // B row (output col) 0..63
    int bq = tid >> 6;          // B k-quarter (16 floats each)

    for (int k0 = 0; k0 < GK; k0 += VB_BK) {
        // ---- stage A: 128x64 fp32 -> bf16, swizzled ----
        {
            int gi = i0 + ar;
            const float4* src = (const float4*)(X + (size_t)gi * GK + k0 + ah * 32);
            float4 f[8];
            #pragma unroll
            for (int j = 0; j < 8; ++j)
                f[j] = (gi < M) ? src[j] : make_float4(0.f, 0.f, 0.f, 0.f);
            #pragma unroll
            for (int jj = 0; jj < 4; ++jj) {
                uint4 wv;
                wv.x = pk2(f[jj*2].x,   f[jj*2].y);
                wv.y = pk2(f[jj*2].z,   f[jj*2].w);
                wv.z = pk2(f[jj*2+1].x, f[jj*2+1].y);
                wv.w = pk2(f[jj*2+1].z, f[jj*2+1].w);
                int addr = ar * 128 + ah * 64 + jj * 16;
                addr ^= (ar & 7) << 4;
                *(uint4*)(smem + addr) = wv;
            }
        }
        // ---- stage B: 64x64 fp32 -> bf16, swizzled ----
        {
            int go = o0 + br;
            const float4* src = (const float4*)(W + (size_t)go * GK + k0 + bq * 16);
            float4 f[4];
            #pragma unroll
            for (int j = 0; j < 4; ++j) f[j] = src[j];
            #pragma unroll
            for (int jj = 0; jj < 2; ++jj) {
                uint4 wv;
                wv.x = pk2(f[jj*2].x,   f[jj*2].y);
                wv.y = pk2(f[jj*2].z,   f[jj*2].w);
                wv.z = pk2(f[jj*2+1].x, f[jj*2+1].y);
                wv.w = pk2(f[jj*2+1].z, f[jj*2+1].w);
                int addr = VB_BOFF + br * 128 + bq * 32 + jj * 16;
                addr ^= (br & 7) << 4;
                *(uint4*)(smem + addr) = wv;
            }
        }
        __syncthreads();

        // ---- compute: 2 k-steps of 32 ----
        #pragma unroll
        for (int ks = 0; ks < 2; ++ks) {
            int kbyte = ks * 64 + (lane >> 4) * 16;
            bf16x8 af[4], bf[2];
            #pragma unroll
            for (int mi = 0; mi < 4; ++mi) {
                int row = wr * 64 + mi * 16 + (lane & 15);
                int addr = row * 128 + kbyte;
                addr ^= (row & 7) << 4;
                af[mi] = *(const bf16x8*)(smem + addr);
            }
            #pragma unroll
            for (int ni = 0; ni < 2; ++ni) {
                int row = wc * 32 + ni * 16 + (lane & 15);
                int addr = VB_BOFF + row * 128 + kbyte;
                addr ^= (row & 7) << 4;
                bf[ni] = *(const bf16x8*)(smem + addr);
            }
            #pragma unroll
            for (int mi = 0; mi < 4; ++mi)
                #pragma unroll
                for (int ni = 0; ni < 2; ++ni)
                    acc[mi][ni] = __builtin_amdgcn_mfma_f32_16x16x32_bf16(
                        af[mi], bf[ni], acc[mi][ni], 0, 0, 0);
        }
        __syncthreads();
    }

    // ---- epilogue: +bias, cvt bf16, store ----
    #pragma unroll
    for (int mi = 0; mi < 4; ++mi) {
        #pragma unroll
        for (int j = 0; j < 4; ++j) {
            int grow = i0 + wr * 64 + mi * 16 + (lane >> 4) * 4 + j;
            if (grow < M) {
                #pragma unroll
                for (int ni = 0; ni < 2; ++ni) {
                    int gcol = o0 + wc * 32 + ni * 16 + (lane & 15);
                    float v = acc[mi][ni][j] + bias[gcol];
                    out[(size_t)grow * DMODEL + gcol] = __bfloat16_as_ushort(__float2bfloat16(v));
                }
            }
        }
    }
}

// ---------------- generic fp32 GEMM (small GEMMs) ----------------
__global__ __launch_bounds__(256)
void gemm_bias(const float* __restrict__ X, const float* __restrict__ W,
               const float* __restrict__ bias, float* __restrict__ out,
               int M, int N) {
    const int BM = 64, BN = 64, BK = 32;
    __shared__ float Xs[BK][BM + 4];
    __shared__ float Ws[BK][BN + 4];
    int i0 = blockIdx.x * BM;
    int o0 = blockIdx.y * BN;
    int tid = threadIdx.x;
    int ty = tid >> 4, tx = tid & 15;
    float acc[4][4] = {};
    int r  = tid >> 3;
    int kq = (tid & 7) * 4;
    for (int k0 = 0; k0 < GK; k0 += BK) {
        #pragma unroll
        for (int rr = r; rr < BM; rr += 32) {
            int gi = i0 + rr;
            float4 v = (gi < M) ? *(const float4*)(X + (size_t)gi*GK + k0 + kq)
                                : make_float4(0.f,0.f,0.f,0.f);
            Xs[kq+0][rr] = v.x; Xs[kq+1][rr] = v.y;
            Xs[kq+2][rr] = v.z; Xs[kq+3][rr] = v.w;
        }
        #pragma unroll
        for (int rr = r; rr < BN; rr += 32) {
            int go = o0 + rr;
            float4 v = *(const float4*)(W + (size_t)go*GK + k0 + kq);
            Ws[kq+0][rr] = v.x; Ws[kq+1][rr] = v.y;
            Ws[kq+2][rr] = v.z; Ws[kq+3][rr] = v.w;
        }
        __syncthreads();
        #pragma unroll
        for (int kk = 0; kk < BK; ++kk) {
            float4 av = *(const float4*)&Xs[kk][ty*4];
            float4 bv = *(const float4*)&Ws[kk][tx*4];
            float aa[4] = {av.x, av.y, av.z, av.w};
            float bb[4] = {bv.x, bv.y, bv.z, bv.w};
            #pragma unroll
            for (int ii = 0; ii < 4; ++ii)
                #pragma unroll
                for (int jj = 0; jj < 4; ++jj)
                    acc[ii][jj] += aa[ii] * bb[jj];
        }
        __syncthreads();
    }
    #pragma unroll
    for (int ii = 0; ii < 4; ++ii) {
        int gi = i0 + ty*4 + ii;
        if (gi < M) {
            #pragma unroll
            for (int jj = 0; jj < 4; ++jj) {
                int go = o0 + tx*4 + jj;
                out[(size_t)gi*N + go] = acc[ii][jj] + bias[go];
            }
        }
    }
}

// ---------------- fused: softmax + locations + bilinear sampling + weighted sum ----------------
__global__ __launch_bounds__(256)
void fused_sample(const float* __restrict__ logits,     // (4000, 512) m*64+p
                  const float* __restrict__ ref_pts,    // (4,1000,2)
                  const unsigned short* __restrict__ value, // bf16 (4, 19822, 256)
                  const float* __restrict__ consts,     // 4*48
                  float* __restrict__ attn_out) {       // (4000, 256)
    int b = blockIdx.x;
    int n = b / LQ;
    int q = b - n * LQ;
    int tid = threadIdx.x;

    __shared__ float s_attn[512];
    __shared__ float s_loc[16][2];
    __shared__ int   s_idx[64][4];
    __shared__ float s_w[64][4];

    s_attn[tid]       = logits[(size_t)b * 512 + tid];
    s_attn[tid + 256] = logits[(size_t)b * 512 + tid + 256];
    __syncthreads();

    {
        int wave = tid >> 6, lane = tid & 63;
        for (int h = wave; h < NHEAD; h += 4) {
            float v = s_attn[h * 64 + lane];
            float mx = v;
            #pragma unroll
            for (int off = 32; off; off >>= 1) mx = fmaxf(mx, __shfl_xor(mx, off, 64));
            float e = expf(v - mx);
            float sm = e;
            #pragma unroll
            for (int off = 32; off; off >>= 1) sm += __shfl_xor(sm, off, 64);
            s_attn[h * 64 + lane] = e / sm;
        }
    }

    if (tid < 16) {
        const float* C = consts + n * 48;
        float rx = ref_pts[((size_t)n * LQ + q) * 2 + 0];
        float ry = ref_pts[((size_t)n * LQ + q) * 2 + 1];
        float dx = rx - C[4], dy = ry - C[5];
        float ox = (C[0]*dx + C[1]*dy) * IMGF;
        float oy = (C[2]*dx + C[3]*dy) * IMGF;
        float u0 = ox - C[15], u1 = oy - C[16], u2 = 1.0f - C[17];
        float r0 = C[6]*u0  + C[7]*u1  + C[8]*u2;
        float r1 = C[9]*u0  + C[10]*u1 + C[11]*u2;
        float r2 = C[12]*u0 + C[13]*u1 + C[14]*u2;
        float y0 = C[18]*r0 + C[19]*r1 + C[20]*r2 + C[21];
        float y1 = C[22]*r0 + C[23]*r1 + C[24]*r2 + C[25];
        float y2 = C[26]*r0 + C[27]*r1 + C[28]*r2 + C[29];
        float inv = 1.0f/(y2 + 1e-8f);
        float prx = y0*inv, pry = y1*inv;
        float ts0 = C[30], ts1 = C[31];
        float msx = (prx - ts0) / IMGF, msy = (pry - ts1) / IMGF;
        int j = tid;
        float xsj = IMGF * ((float)j / 15.0f);
        float lx = (ts0 + msx * xsj) / IMGF;
        float ly = (ts1 + msy * xsj) / IMGF;
        float Lx = C[32]*lx + C[33]*ly + C[34];
        float Ly = C[35]*lx + C[36]*ly + C[37];
        s_loc[j][0] = fminf(fmaxf(Lx, 0.0f), 1.0f);
        s_loc[j][1] = fminf(fmaxf(Ly, 0.0f), 1.0f);
    }
    __syncthreads();

    if (tid < 64) {
        int p = tid, lev = p >> 4, j = p & 15;
        int H = c_LH[lev], W = c_LW[lev], st = c_LST[lev];
        float gx = s_loc[j][0] * (float)W - 0.5f;
        float gy = s_loc[j][1] * (float)H - 0.5f;
        float x0f = floorf(gx), y0f = floorf(gy);
        float wx = gx - x0f, wy = gy - y0f;
        int x0 = (int)x0f, y0 = (int)y0f;
        int x1 = x0 + 1, y1 = y0 + 1;
        bool vx0 = (x0 >= 0) & (x0 < W), vx1 = (x1 >= 0) & (x1 < W);
        bool vy0 = (y0 >= 0) & (y0 < H), vy1 = (y1 >= 0) & (y1 < H);
        s_idx[p][0] = (vx0 & vy0) ? st + y0 * W + x0 : -1;  s_w[p][0] = (1.f-wx)*(1.f-wy);
        s_idx[p][1] = (vx1 & vy0) ? st + y0 * W + x1 : -1;  s_w[p][1] = wx*(1.f-wy);
        s_idx[p][2] = (vx0 & vy1) ? st + y1 * W + x0 : -1;  s_w[p][2] = (1.f-wx)*wy;
        s_idx[p][3] = (vx1 & vy1) ? st + y1 * W + x1 : -1;  s_w[p][3] = wx*wy;
    }
    __syncthreads();

    // gather + weighted sum; value batch is swap_pairs -> n^1
    const unsigned short* vbase = value + (size_t)(n ^ 1) * STOT * DMODEL;
    int m = tid >> 5;
    float acc = 0.0f;
    for (int p = 0; p < 64; ++p) {
        float wa = s_attn[m * 64 + p];
        float s = 0.0f;
        #pragma unroll
        for (int cc = 0; cc < 4; ++cc) {
            int idx = s_idx[p][cc];
            if (idx >= 0) {
                float v = __bfloat162float(__ushort_as_bfloat16(vbase[(size_t)idx * DMODEL + tid]));
                s += s_w[p][cc] * v;
            }
        }
        acc += wa * s;
    }
    attn_out[(size_t)b * DMODEL + tid] = acc;
}

// ---------------- launch ----------------
extern "C" void kernel_launch(void* const* d_in, const int* in_sizes, int n_in,
                              void* d_out, int out_size, void* d_ws, size_t ws_size,
                              hipStream_t stream) {
    const float* query         = (const float*)d_in[0];
    const float* input_flatten = (const float*)d_in[1];
    const float* ref_pts       = (const float*)d_in[2];
    const float* p_pfws        = (const float*)d_in[3];
    const float* pt            = (const float*)d_in[4];
    const float* W_val         = (const float*)d_in[5];
    const float* b_val         = (const float*)d_in[6];
    const float* W_attn        = (const float*)d_in[7];
    const float* b_attn        = (const float*)d_in[8];
    const float* W_out         = (const float*)d_in[9];
    const float* b_out         = (const float*)d_in[10];
    float* out = (float*)d_out;

    const int M = NB * STOT;                                   // 79288
    const size_t value_bytes  = (size_t)M * DMODEL * 2;        // bf16
    const size_t logits_bytes = (size_t)NB * LQ * 512 * 4;
    const size_t attn_bytes   = (size_t)NB * LQ * DMODEL * 4;
    const size_t consts_bytes = NB * 48 * 4;
    const size_t need = value_bytes + logits_bytes + attn_bytes + consts_bytes;
    if (ws_size < need) return;

    unsigned short* value = (unsigned short*)d_ws;
    float* logits   = (float*)((char*)d_ws + value_bytes);
    float* attn_out = (float*)((char*)d_ws + value_bytes + logits_bytes);
    float* consts   = (float*)((char*)d_ws + value_bytes + logits_bytes + attn_bytes);

    setup_consts<<<1, 64, 0, stream>>>(p_pfws, pt, consts);

    {   // value = bf16(input_flatten @ W_val.T + b_val)
        dim3 g((M + VB_BM - 1) / VB_BM, DMODEL / VB_BN);
        gemm_val_bf16<<<g, 256, 0, stream>>>(input_flatten, W_val, b_val, value, M);
    }
    {   // logits = query @ W_attn.T + b_attn
        dim3 g((NB * LQ + 63) / 64, 512 / 64);
        gemm_bias<<<g, 256, 0, stream>>>(query, W_attn, b_attn, logits, NB * LQ, 512);
    }
    fused_sample<<<NB * LQ, 256, 0, stream>>>(logits, ref_pts, value, consts, attn_out);
    {   // out = attn_out @ W_out.T + b_out
        dim3 g((NB * LQ + 63) / 64, DMODEL / 64);
        gemm_bias<<<g, 256, 0, stream>>>(attn_out, W_out, b_out, out, NB * LQ, DMODEL);
    }
}

// Round 3
// 125.235 us; speedup vs baseline: 2.4845x; 2.4845x over previous
//
#include <hip/hip_runtime.h>
#include <hip/hip_bf16.h>
#include <math.h>

// ---------------- problem constants ----------------
#define NB 4          // batch
#define LQ 1000       // queries
#define NHEAD 8
#define DHEAD 32
#define DMODEL 256
#define PSUM 64       // points per head (4 levels x 16)
#define STOT 19822    // total spatial size
#define IMGF 976.0f
#define GK 256        // K dim of all GEMMs

__device__ __constant__ int c_LH[4] = {122, 61, 31, 16};
__device__ __constant__ int c_LW[4] = {122, 61, 31, 16};
__device__ __constant__ int c_LST[4] = {0, 14884, 18605, 19566};

typedef __attribute__((ext_vector_type(8))) short bf16x8;
typedef __attribute__((ext_vector_type(4))) float f32x4;

__device__ inline unsigned int pk2(float a, float b) {
    unsigned short ua = __bfloat16_as_ushort(__float2bfloat16(a));
    unsigned short ub = __bfloat16_as_ushort(__float2bfloat16(b));
    return (unsigned int)ua | ((unsigned int)ub << 16);
}
__device__ inline float bf2f(unsigned short u) {
    return __uint_as_float(((unsigned int)u) << 16);
}

// ---------------- setup: per-batch constant matrices ----------------
__global__ void setup_consts(const float* __restrict__ p_pfws,
                             const float* __restrict__ pt,
                             float* __restrict__ consts) {
    int n = threadIdx.x;
    if (n >= NB) return;
    const float* P1 = p_pfws + n * 12;
    const float* P2 = p_pfws + (n ^ 1) * 12;
    const float* T  = pt + n * 6;
    const float* T2 = pt + (n ^ 1) * 6;
    float* C = consts + n * 48;
    float det = T[0]*T[4] - T[1]*T[3];
    float idet = 1.0f/det;
    C[0] =  T[4]*idet; C[1] = -T[1]*idet;
    C[2] = -T[3]*idet; C[3] =  T[0]*idet;
    C[4] = T[2]; C[5] = T[5];
    float a=P1[0], b=P1[1], c=P1[2];
    float d=P1[4], e=P1[5], f=P1[6];
    float g=P1[8], h=P1[9], i=P1[10];
    float b10=P1[3], b11=P1[7], b12=P1[11];
    float A_=e*i-f*h, B_=c*h-b*i, Cc=b*f-c*e;
    float D_=f*g-d*i, E_=a*i-c*g, F_=c*d-a*f;
    float G_=d*h-e*g, H_=b*g-a*h, I_=a*e-b*d;
    float det3 = a*A_ + b*D_ + c*G_;
    float id3 = 1.0f/det3;
    C[6]=A_*id3;  C[7]=B_*id3;  C[8]=Cc*id3;
    C[9]=D_*id3;  C[10]=E_*id3; C[11]=F_*id3;
    C[12]=G_*id3; C[13]=H_*id3; C[14]=I_*id3;
    C[15]=b10; C[16]=b11; C[17]=b12;
    for (int k = 0; k < 12; ++k) C[18+k] = P2[k];
    float cam0 = -(C[6]*b10  + C[7]*b11  + C[8]*b12);
    float cam1 = -(C[9]*b10  + C[10]*b11 + C[11]*b12);
    float cam2 = -(C[12]*b10 + C[13]*b11 + C[14]*b12);
    float y0 = P2[0]*cam0 + P2[1]*cam1 + P2[2]*cam2  + P2[3];
    float y1 = P2[4]*cam0 + P2[5]*cam1 + P2[6]*cam2  + P2[7];
    float y2 = P2[8]*cam0 + P2[9]*cam1 + P2[10]*cam2 + P2[11];
    float inv = 1.0f/(y2 + 1e-8f);
    C[30] = y0*inv; C[31] = y1*inv;
    for (int k = 0; k < 6; ++k) C[32+k] = T2[k];
}

// ---------------- W fp32 -> bf16 (one-time, 64 blocks) ----------------
__global__ void convert_w(const float* __restrict__ W, unsigned short* __restrict__ Wb) {
    int i = (blockIdx.x * 256 + threadIdx.x) * 4;   // 65536 elements / 4
    float4 f = *(const float4*)(W + i);
    ushort4 o;
    o.x = __bfloat16_as_ushort(__float2bfloat16(f.x));
    o.y = __bfloat16_as_ushort(__float2bfloat16(f.y));
    o.z = __bfloat16_as_ushort(__float2bfloat16(f.z));
    o.w = __bfloat16_as_ushort(__float2bfloat16(f.w));
    *(ushort4*)(Wb + i) = o;
}

// ---------------- bf16 MFMA GEMM: value = bf16( X @ Wb.T + bias ) ----------------
// X fp32 MxK row-major (converted on the fly), Wb bf16 256xK row-major, K=256.
// BM=128, BN=256 (full width -> X read ONCE), BK=64. 512 threads = 8 waves (2x4),
// each wave 64x64 out (4x4 frags). LDS: A 16KB + B 32KB, XOR-swizzled (G4/T2).
#define VB_BM 128
#define VB_BK 64
#define VB_BOFF 16384

__global__ __launch_bounds__(512, 4)
void gemm_val_bf16(const float* __restrict__ X, const unsigned short* __restrict__ Wb,
                   const float* __restrict__ bias, unsigned short* __restrict__ out,
                   int M) {
    __shared__ char smem[16384 + 32768];
    int i0 = blockIdx.x * VB_BM;
    int tid = threadIdx.x;
    int lane = tid & 63;
    int w = tid >> 6;                 // 0..7
    int wr = w >> 2, wc = w & 3;      // 2 x 4 wave grid

    f32x4 acc[4][4] = {};

    int ar = tid >> 2;                // A row 0..127
    int aq = tid & 3;                 // quarter: 16 floats = 64B fp32 -> 32B bf16
    int br = tid >> 1;                // B row (output col) 0..255
    int bh = tid & 1;                 // half: 32 bf16 = 64B

    #pragma unroll 1
    for (int k0 = 0; k0 < GK; k0 += VB_BK) {
        // ---- stage A: load 16 fp32, convert, swizzled write (2 x 16B) ----
        {
            int gi = i0 + ar;
            const float4* src = (const float4*)(X + (size_t)gi * GK + k0 + aq * 16);
            float4 f0, f1, f2, f3;
            if (gi < M) { f0 = src[0]; f1 = src[1]; f2 = src[2]; f3 = src[3]; }
            else { f0 = f1 = f2 = f3 = make_float4(0.f,0.f,0.f,0.f); }
            uint4 wv0, wv1;
            wv0.x = pk2(f0.x,f0.y); wv0.y = pk2(f0.z,f0.w);
            wv0.z = pk2(f1.x,f1.y); wv0.w = pk2(f1.z,f1.w);
            wv1.x = pk2(f2.x,f2.y); wv1.y = pk2(f2.z,f2.w);
            wv1.z = pk2(f3.x,f3.y); wv1.w = pk2(f3.z,f3.w);
            int base = ar * 128 + aq * 32;
            int sw = (ar & 7) << 4;
            *(uint4*)(smem + ((base     ) ^ sw)) = wv0;
            *(uint4*)(smem + ((base + 16) ^ sw)) = wv1;
        }
        // ---- stage B: bf16 direct, swizzled write (4 x 16B) ----
        {
            const uint4* src = (const uint4*)(Wb + (size_t)br * GK + k0 + bh * 32);
            uint4 b0 = src[0], b1 = src[1], b2 = src[2], b3 = src[3];
            int base = VB_BOFF + br * 128 + bh * 64;
            int sw = (br & 7) << 4;
            *(uint4*)(smem + ((base     ) ^ sw)) = b0;
            *(uint4*)(smem + ((base + 16) ^ sw)) = b1;
            *(uint4*)(smem + ((base + 32) ^ sw)) = b2;
            *(uint4*)(smem + ((base + 48) ^ sw)) = b3;
        }
        __syncthreads();

        #pragma unroll
        for (int ks = 0; ks < 2; ++ks) {
            int kbyte = ks * 64 + (lane >> 4) * 16;
            bf16x8 af[4], bfr[4];
            #pragma unroll
            for (int mi = 0; mi < 4; ++mi) {
                int row = wr * 64 + mi * 16 + (lane & 15);
                af[mi] = *(const bf16x8*)(smem + ((row * 128 + kbyte) ^ ((row & 7) << 4)));
            }
            #pragma unroll
            for (int ni = 0; ni < 4; ++ni) {
                int row = wc * 64 + ni * 16 + (lane & 15);
                bfr[ni] = *(const bf16x8*)(smem + ((VB_BOFF + row * 128 + kbyte) ^ ((row & 7) << 4)));
            }
            #pragma unroll
            for (int mi = 0; mi < 4; ++mi)
                #pragma unroll
                for (int ni = 0; ni < 4; ++ni)
                    acc[mi][ni] = __builtin_amdgcn_mfma_f32_16x16x32_bf16(
                        af[mi], bfr[ni], acc[mi][ni], 0, 0, 0);
        }
        __syncthreads();
    }

    // ---- epilogue: +bias, cvt bf16, store ----
    #pragma unroll
    for (int mi = 0; mi < 4; ++mi) {
        #pragma unroll
        for (int j = 0; j < 4; ++j) {
            int grow = i0 + wr * 64 + mi * 16 + (lane >> 4) * 4 + j;
            if (grow < M) {
                #pragma unroll
                for (int ni = 0; ni < 4; ++ni) {
                    int gcol = wc * 64 + ni * 16 + (lane & 15);
                    float v = acc[mi][ni][j] + bias[gcol];
                    out[(size_t)grow * DMODEL + gcol] = __bfloat16_as_ushort(__float2bfloat16(v));
                }
            }
        }
    }
}

// ---------------- generic fp32 GEMM (small GEMMs) ----------------
__global__ __launch_bounds__(256)
void gemm_bias(const float* __restrict__ X, const float* __restrict__ W,
               const float* __restrict__ bias, float* __restrict__ out,
               int M, int N) {
    const int BM = 64, BN = 64, BK = 32;
    __shared__ float Xs[BK][BM + 4];
    __shared__ float Ws[BK][BN + 4];
    int i0 = blockIdx.x * BM;
    int o0 = blockIdx.y * BN;
    int tid = threadIdx.x;
    int ty = tid >> 4, tx = tid & 15;
    float acc[4][4] = {};
    int r  = tid >> 3;
    int kq = (tid & 7) * 4;
    for (int k0 = 0; k0 < GK; k0 += BK) {
        #pragma unroll
        for (int rr = r; rr < BM; rr += 32) {
            int gi = i0 + rr;
            float4 v = (gi < M) ? *(const float4*)(X + (size_t)gi*GK + k0 + kq)
                                : make_float4(0.f,0.f,0.f,0.f);
            Xs[kq+0][rr] = v.x; Xs[kq+1][rr] = v.y;
            Xs[kq+2][rr] = v.z; Xs[kq+3][rr] = v.w;
        }
        #pragma unroll
        for (int rr = r; rr < BN; rr += 32) {
            int go = o0 + rr;
            float4 v = *(const float4*)(W + (size_t)go*GK + k0 + kq);
            Ws[kq+0][rr] = v.x; Ws[kq+1][rr] = v.y;
            Ws[kq+2][rr] = v.z; Ws[kq+3][rr] = v.w;
        }
        __syncthreads();
        #pragma unroll
        for (int kk = 0; kk < BK; ++kk) {
            float4 av = *(const float4*)&Xs[kk][ty*4];
            float4 bv = *(const float4*)&Ws[kk][tx*4];
            float aa[4] = {av.x, av.y, av.z, av.w};
            float bb[4] = {bv.x, bv.y, bv.z, bv.w};
            #pragma unroll
            for (int ii = 0; ii < 4; ++ii)
                #pragma unroll
                for (int jj = 0; jj < 4; ++jj)
                    acc[ii][jj] += aa[ii] * bb[jj];
        }
        __syncthreads();
    }
    #pragma unroll
    for (int ii = 0; ii < 4; ++ii) {
        int gi = i0 + ty*4 + ii;
        if (gi < M) {
            #pragma unroll
            for (int jj = 0; jj < 4; ++jj) {
                int go = o0 + tx*4 + jj;
                out[(size_t)gi*N + go] = acc[ii][jj] + bias[go];
            }
        }
    }
}

// ---------------- fused: softmax + locations + bilinear sampling + weighted sum ----------------
// one block per (n,q); 4 waves; wave w handles level w's 16 points.
// Each lane owns 4 channels (lane*4..lane*4+3) -> ushort4 gathers, 512B/wave/instr.
__global__ __launch_bounds__(256)
void fused_sample(const float* __restrict__ logits,        // (4000, 512) m*64+p
                  const float* __restrict__ ref_pts,       // (4,1000,2)
                  const unsigned short* __restrict__ value,// bf16 (4, 19822, 256)
                  const float* __restrict__ consts,        // 4*48
                  float* __restrict__ attn_out) {          // (4000, 256)
    int b = blockIdx.x;
    int n = b / LQ;
    int q = b - n * LQ;
    int tid = threadIdx.x;

    __shared__ float s_attn[512];
    __shared__ float s_loc[16][2];
    __shared__ int   s_idx[64][4];
    __shared__ float s_w[64][4];
    __shared__ float4 s_part[4][64];

    s_attn[tid]       = logits[(size_t)b * 512 + tid];
    s_attn[tid + 256] = logits[(size_t)b * 512 + tid + 256];
    __syncthreads();

    {   // softmax per head
        int wave = tid >> 6, lane = tid & 63;
        for (int h = wave; h < NHEAD; h += 4) {
            float v = s_attn[h * 64 + lane];
            float mx = v;
            #pragma unroll
            for (int off = 32; off; off >>= 1) mx = fmaxf(mx, __shfl_xor(mx, off, 64));
            float e = expf(v - mx);
            float sm = e;
            #pragma unroll
            for (int off = 32; off; off >>= 1) sm += __shfl_xor(sm, off, 64);
            s_attn[h * 64 + lane] = e / sm;
        }
    }

    if (tid < 16) {   // 16 distinct sampling locations (shared by all 4 levels)
        const float* C = consts + n * 48;
        float rx = ref_pts[((size_t)n * LQ + q) * 2 + 0];
        float ry = ref_pts[((size_t)n * LQ + q) * 2 + 1];
        float dx = rx - C[4], dy = ry - C[5];
        float ox = (C[0]*dx + C[1]*dy) * IMGF;
        float oy = (C[2]*dx + C[3]*dy) * IMGF;
        float u0 = ox - C[15], u1 = oy - C[16], u2 = 1.0f - C[17];
        float r0 = C[6]*u0  + C[7]*u1  + C[8]*u2;
        float r1 = C[9]*u0  + C[10]*u1 + C[11]*u2;
        float r2 = C[12]*u0 + C[13]*u1 + C[14]*u2;
        float y0 = C[18]*r0 + C[19]*r1 + C[20]*r2 + C[21];
        float y1 = C[22]*r0 + C[23]*r1 + C[24]*r2 + C[25];
        float y2 = C[26]*r0 + C[27]*r1 + C[28]*r2 + C[29];
        float inv = 1.0f/(y2 + 1e-8f);
        float prx = y0*inv, pry = y1*inv;
        float ts0 = C[30], ts1 = C[31];
        float msx = (prx - ts0) / IMGF, msy = (pry - ts1) / IMGF;
        int j = tid;
        float xsj = IMGF * ((float)j / 15.0f);
        float lx = (ts0 + msx * xsj) / IMGF;
        float ly = (ts1 + msy * xsj) / IMGF;
        float Lx = C[32]*lx + C[33]*ly + C[34];
        float Ly = C[35]*lx + C[36]*ly + C[37];
        s_loc[j][0] = fminf(fmaxf(Lx, 0.0f), 1.0f);
        s_loc[j][1] = fminf(fmaxf(Ly, 0.0f), 1.0f);
    }
    __syncthreads();

    if (tid < 64) {   // bilinear metadata per point
        int p = tid, lev = p >> 4, j = p & 15;
        int H = c_LH[lev], W = c_LW[lev], st = c_LST[lev];
        float gx = s_loc[j][0] * (float)W - 0.5f;
        float gy = s_loc[j][1] * (float)H - 0.5f;
        float x0f = floorf(gx), y0f = floorf(gy);
        float wx = gx - x0f, wy = gy - y0f;
        int x0 = (int)x0f, y0 = (int)y0f;
        int x1 = x0 + 1, y1 = y0 + 1;
        bool vx0 = (x0 >= 0) & (x0 < W), vx1 = (x1 >= 0) & (x1 < W);
        bool vy0 = (y0 >= 0) & (y0 < H), vy1 = (y1 >= 0) & (y1 < H);
        s_idx[p][0] = (vx0 & vy0) ? st + y0 * W + x0 : -1;  s_w[p][0] = (1.f-wx)*(1.f-wy);
        s_idx[p][1] = (vx1 & vy0) ? st + y0 * W + x1 : -1;  s_w[p][1] = wx*(1.f-wy);
        s_idx[p][2] = (vx0 & vy1) ? st + y1 * W + x0 : -1;  s_w[p][2] = (1.f-wx)*wy;
        s_idx[p][3] = (vx1 & vy1) ? st + y1 * W + x1 : -1;  s_w[p][3] = wx*wy;
    }
    __syncthreads();

    // gather + weighted sum; value batch is swap_pairs -> n^1
    int wv = tid >> 6, lane = tid & 63;
    const unsigned short* vbase = value + (size_t)(n ^ 1) * STOT * DMODEL + lane * 4;
    int m = lane >> 3;   // head of channel lane*4
    float a0 = 0.f, a1 = 0.f, a2 = 0.f, a3 = 0.f;
    #pragma unroll 4
    for (int j = 0; j < 16; ++j) {
        int p = wv * 16 + j;
        float wa = s_attn[m * 64 + p];
        float s0 = 0.f, s1 = 0.f, s2 = 0.f, s3 = 0.f;
        #pragma unroll
        for (int cc = 0; cc < 4; ++cc) {
            int idx = s_idx[p][cc];
            if (idx >= 0) {
                ushort4 vv = *(const ushort4*)(vbase + (size_t)idx * DMODEL);
                float wgt = s_w[p][cc];
                s0 += wgt * bf2f(vv.x);
                s1 += wgt * bf2f(vv.y);
                s2 += wgt * bf2f(vv.z);
                s3 += wgt * bf2f(vv.w);
            }
        }
        a0 += wa * s0; a1 += wa * s1; a2 += wa * s2; a3 += wa * s3;
    }
    s_part[wv][lane] = make_float4(a0, a1, a2, a3);
    __syncthreads();

    const float* sp = (const float*)s_part;
    float r = sp[tid] + sp[256 + tid] + sp[512 + tid] + sp[768 + tid];
    attn_out[(size_t)b * DMODEL + tid] = r;
}

// ---------------- launch ----------------
extern "C" void kernel_launch(void* const* d_in, const int* in_sizes, int n_in,
                              void* d_out, int out_size, void* d_ws, size_t ws_size,
                              hipStream_t stream) {
    const float* query         = (const float*)d_in[0];
    const float* input_flatten = (const float*)d_in[1];
    const float* ref_pts       = (const float*)d_in[2];
    const float* p_pfws        = (const float*)d_in[3];
    const float* pt            = (const float*)d_in[4];
    const float* W_val         = (const float*)d_in[5];
    const float* b_val         = (const float*)d_in[6];
    const float* W_attn        = (const float*)d_in[7];
    const float* b_attn        = (const float*)d_in[8];
    const float* W_out         = (const float*)d_in[9];
    const float* b_out         = (const float*)d_in[10];
    float* out = (float*)d_out;

    const int M = NB * STOT;                                   // 79288
    const size_t value_bytes  = (size_t)M * DMODEL * 2;        // bf16
    const size_t logits_bytes = (size_t)NB * LQ * 512 * 4;
    const size_t attn_bytes   = (size_t)NB * LQ * DMODEL * 4;
    const size_t consts_bytes = NB * 48 * 4;
    const size_t wb_bytes     = (size_t)DMODEL * DMODEL * 2;   // bf16 W_val
    const size_t need = value_bytes + logits_bytes + attn_bytes + consts_bytes + wb_bytes;
    if (ws_size < need) return;

    unsigned short* value = (unsigned short*)d_ws;
    float* logits   = (float*)((char*)d_ws + value_bytes);
    float* attn_out = (float*)((char*)d_ws + value_bytes + logits_bytes);
    float* consts   = (float*)((char*)d_ws + value_bytes + logits_bytes + attn_bytes);
    unsigned short* wbf = (unsigned short*)((char*)d_ws + value_bytes + logits_bytes + attn_bytes + consts_bytes);

    setup_consts<<<1, 64, 0, stream>>>(p_pfws, pt, consts);
    convert_w<<<64, 256, 0, stream>>>(W_val, wbf);

    {   // value = bf16(input_flatten @ W_val.T + b_val), X read once
        dim3 g((M + VB_BM - 1) / VB_BM, 1);
        gemm_val_bf16<<<g, 512, 0, stream>>>(input_flatten, wbf, b_val, value, M);
    }
    {   // logits = query @ W_attn.T + b_attn
        dim3 g((NB * LQ + 63) / 64, 512 / 64);
        gemm_bias<<<g, 256, 0, stream>>>(query, W_attn, b_attn, logits, NB * LQ, 512);
    }
    fused_sample<<<NB * LQ, 256, 0, stream>>>(logits, ref_pts, value, consts, attn_out);
    {   // out = attn_out @ W_out.T + b_out
        dim3 g((NB * LQ + 63) / 64, DMODEL / 64);
        gemm_bias<<<g, 256, 0, stream>>>(attn_out, W_out, b_out, out, NB * LQ, DMODEL);
    }
}